// Round 3
// baseline (361.132 us; speedup 1.0000x reference)
//
#include <hip/hip_runtime.h>

#define S_DIM 256
#define N_HM 32
#define K_APP 16

typedef _Float16 half8_t __attribute__((ext_vector_type(8)));
typedef float f32x4 __attribute__((ext_vector_type(4)));

// ---------------------------------------------------------------------------
// Kernel 1: one WAVE per (b, h, n-half). No LDS, no barriers, no cross-wave
// communication. Per wave:
//   A = x[b, :, h, :]        (16 x-channels = MFMA M)
//   B = exp(raw[b, n0:n0+16, h, :])  (16 heatmap rows = MFMA N)
//   C[k][n] += A.B over w (8 chunks of K=32), then scale col n by 1/rowsum.
// Fragment sourcing is straight from global: lane(col=lane&15, q=lane>>4)
// holds A[col][q*8+j] and B_row=col at w = c*32 + q*8 + j  (8 contiguous
// floats -> 2 float4 loads each). Row-sum over w = local 64-elem sum then
// xor-shuffle over the 4 q-groups (masks 16, 32).
// Writes normalized partial[pair][n0+col][k] -- one contiguous 1KB per wave.
// ---------------------------------------------------------------------------
__global__ __launch_bounds__(256) void k1_softmax_pool(
    const float* __restrict__ x,     // [B,16,256,256]
    const float* __restrict__ raw,   // [B,32,256,256]
    float* __restrict__ partial)     // [4096][32][16]
{
    const int wid  = threadIdx.x >> 6;
    const int lane = threadIdx.x & 63;
    const int gw   = blockIdx.x * 4 + wid;    // 0..8191
    const int pair = gw >> 1;                 // (b,h) 0..4095
    const int nh   = gw & 1;                  // n-half
    const int b    = pair >> 8;
    const int h    = pair & 255;
    const int col  = lane & 15;
    const int q    = lane >> 4;

    const float* rp = raw + (((size_t)(b * N_HM + nh * 16 + col)) << 16) + (h << 8);
    const float* xp = x   + (((size_t)(b * K_APP + col)) << 16) + (h << 8);

    f32x4 acc = {0.f, 0.f, 0.f, 0.f};
    float ssum = 0.f;

    #pragma unroll
    for (int c = 0; c < 8; ++c) {
        const int w0 = c * 32 + q * 8;
        float4 r0 = *(const float4*)(rp + w0);
        float4 r1 = *(const float4*)(rp + w0 + 4);
        float4 x0 = *(const float4*)(xp + w0);
        float4 x1 = *(const float4*)(xp + w0 + 4);

        float e0 = __expf(r0.x), e1 = __expf(r0.y), e2 = __expf(r0.z), e3 = __expf(r0.w);
        float e4 = __expf(r1.x), e5 = __expf(r1.y), e6 = __expf(r1.z), e7 = __expf(r1.w);
        ssum += ((e0 + e1) + (e2 + e3)) + ((e4 + e5) + (e6 + e7));

        half8_t a, bb;
        a[0] = (_Float16)x0.x; a[1] = (_Float16)x0.y; a[2] = (_Float16)x0.z; a[3] = (_Float16)x0.w;
        a[4] = (_Float16)x1.x; a[5] = (_Float16)x1.y; a[6] = (_Float16)x1.z; a[7] = (_Float16)x1.w;
        bb[0] = (_Float16)e0;  bb[1] = (_Float16)e1;  bb[2] = (_Float16)e2;  bb[3] = (_Float16)e3;
        bb[4] = (_Float16)e4;  bb[5] = (_Float16)e5;  bb[6] = (_Float16)e6;  bb[7] = (_Float16)e7;

        acc = __builtin_amdgcn_mfma_f32_16x16x32_f16(a, bb, acc, 0, 0, 0);
    }

    // full softmax row-sum for row n0+col (q-groups partition w)
    ssum += __shfl_xor(ssum, 16);
    ssum += __shfl_xor(ssum, 32);
    const float inv = 1.0f / ssum;

    // C: col = lane&15 = n_local, row = q*4+reg = k-channel -> contiguous k4
    float* dst = partial + ((size_t)pair << 9) + ((nh * 16 + col) << 4) + (q << 2);
    f32x4 v = {acc.x * inv, acc.y * inv, acc.z * inv, acc.w * inv};
    *(f32x4*)dst = v;
}

// ---------------------------------------------------------------------------
// Kernel 1b: av[b][r] = sum_{h<256} partial[b*256+h][r]   (8192 outputs)
// ---------------------------------------------------------------------------
__global__ __launch_bounds__(256) void k1_reduce(
    const float* __restrict__ partial, float* __restrict__ av)
{
    const int gid = blockIdx.x * 256 + threadIdx.x;   // < 8192
    const int b = gid >> 9;
    const int r = gid & 511;
    const float* p = partial + (((size_t)b) << 17) + r;
    float s = 0.0f;
    #pragma unroll 8
    for (int h = 0; h < 256; ++h) s += p[(size_t)h << 9];
    av[gid] = s;
}

// ---------------------------------------------------------------------------
// Kernel 2: out[b,k,h,w] = (sum_n fit[b,n,h,w]*av[b,n,k]) / (1+sum_n fit)
// 4 pixels per thread (float4 on fit and out); av loads are block-uniform.
// ---------------------------------------------------------------------------
__global__ __launch_bounds__(256) void k2_combine(
    const float* __restrict__ fit,   // [B,32,256,256]
    const float* __restrict__ av,    // [B,32,16]
    float* __restrict__ out)         // [B,16,256,256]
{
    const int tid = threadIdx.x;
    const int b   = blockIdx.x >> 6;                  // 64 blocks per batch
    const int p4  = ((blockIdx.x & 63) << 8) + tid;   // float4 index in 16384

    const float* fb  = fit + (((size_t)(b * N_HM)) << 16) + ((size_t)p4 << 2);
    const float* avb = av + (b << 9);

    float4 num[K_APP];
    #pragma unroll
    for (int k = 0; k < K_APP; ++k) num[k] = make_float4(0.f, 0.f, 0.f, 0.f);
    float4 den = make_float4(1.f, 1.f, 1.f, 1.f);

    #pragma unroll 8
    for (int n = 0; n < N_HM; ++n) {
        float4 f = *(const float4*)(fb + ((size_t)n << 16));
        den.x += f.x; den.y += f.y; den.z += f.z; den.w += f.w;
        const float* a = avb + (n << 4);              // uniform -> scalar loads
        #pragma unroll
        for (int k = 0; k < K_APP; ++k) {
            const float ak = a[k];
            num[k].x += f.x * ak; num[k].y += f.y * ak;
            num[k].z += f.z * ak; num[k].w += f.w * ak;
        }
    }

    const float4 inv = make_float4(1.f / den.x, 1.f / den.y, 1.f / den.z, 1.f / den.w);
    float* ob = out + (((size_t)(b * K_APP)) << 16) + ((size_t)p4 << 2);
    #pragma unroll
    for (int k = 0; k < K_APP; ++k) {
        float4 v = make_float4(num[k].x * inv.x, num[k].y * inv.y,
                               num[k].z * inv.z, num[k].w * inv.w);
        *(float4*)(ob + ((size_t)k << 16)) = v;
    }
}

// ---------------------------------------------------------------------------
extern "C" void kernel_launch(void* const* d_in, const int* in_sizes, int n_in,
                              void* d_out, int out_size, void* d_ws, size_t ws_size,
                              hipStream_t stream)
{
    const float* x   = (const float*)d_in[0];   // [16,16,256,256]
    const float* raw = (const float*)d_in[1];   // [16,32,256,256]
    const float* fit = (const float*)d_in[2];   // [16,32,256,256]
    float* out = (float*)d_out;

    float* av      = (float*)d_ws;              // 8192 floats
    float* partial = (float*)d_ws + 8192;       // 4096*512 floats (8 MB)

    k1_softmax_pool<<<2048, 256, 0, stream>>>(x, raw, partial);
    k1_reduce<<<8192 / 256, 256, 0, stream>>>(partial, av);
    k2_combine<<<16 * 64, 256, 0, stream>>>(fit, av, out);
}